// Round 14
// baseline (503.495 us; speedup 1.0000x reference)
//
#include <hip/hip_runtime.h>

#define NN 50000
#define NE 1600000
#define NR 8
#define ND 128
#define NL 3
#define RN (NR * NN)
#define LN_EPS 1e-5f

// binning: key = dst*8 + et  (node-major), bucket = key>>11
#define NBKT 196          // ceil(400000/2048)
#define BSH 11
#define STRIDE_PB 10240   // stage dwords per bucket (mean 8163, +23 sigma)
#define BIN_BLOCKS 1000   // 1600 edges each
#define EPB 1600
#define I4PB 400
#define MM_BLOCKS_SA ((NN + 127) / 128)      // 391 standalone (NG=2)
#define MM_BLOCKS_FU ((NN + 63) / 64)        // 782 fused (NG=1)

#define PREP_G (NN * 64)
#define PREP_W (27 * 16384)
#define PREP_TOT (PREP_G + PREP_W)
#define PREP_BLOCKS ((PREP_TOT + 255) / 256)

// workspace layout
#define WS_H    0
#define WS_NS   14400000     // nodestart: (NN+1) ints
#define WS_BCUR 16000064
#define WS_ADJ  16004096     // 6.4 MB (packed recs)
#define WS_WB   22404096
#define WS_BIG  23288832     // hr: 9 tables = 115.2 MB
// stage lives in d_out (25.6 MB, dead until last aggln overwrites it)

typedef __attribute__((ext_vector_type(8))) short short8;
typedef __attribute__((ext_vector_type(4))) float float4v;

__device__ __forceinline__ float bflo(unsigned u) { return __uint_as_float(u << 16); }
__device__ __forceinline__ float bfhi(unsigned u) { return __uint_as_float(u & 0xFFFF0000u); }
__device__ __forceinline__ unsigned f2bf(float f) {
    unsigned u = __float_as_uint(f);
    return (u + 0x7FFFu + ((u >> 16) & 1u)) >> 16;   // RNE
}
__device__ __forceinline__ unsigned pack2(float lo, float hi) {
    return f2bf(lo) | (f2bf(hi) << 16);
}

// exclusive 256-scan: intra-wave shfl_up + 4-entry cross-wave fixup.
// ONE barrier (vs 16 for the ping-pong LDS scan). wsum: >=4 ints of LDS.
// Caller must have a barrier between this call's wsum reads and any reuse.
__device__ __forceinline__ int wave_excl_scan256(int own, int tid, int* wsum) {
    int lane = tid & 63, wave = tid >> 6;
    int v = own;
#pragma unroll
    for (int off = 1; off < 64; off <<= 1) {
        int u = __shfl_up(v, off, 64);
        if (lane >= off) v += u;
    }
    if (lane == 63) wsum[wave] = v;
    __syncthreads();
    int woff = 0;
#pragma unroll
    for (int w = 0; w < 4; w++) woff += (w < wave) ? wsum[w] : 0;
    return v + woff - own;
}

// ---- launch 1: binA (blocks [0,1000)) || prep (h gather | wprep) ----
// bcur pre-zeroed on-stream (memset) so binA's atomicAdds are safe (r7 lesson:
// never zero in-grid — block order undefined).
__global__ __launch_bounds__(256) void k_prepbin(const int* __restrict__ x,
                                                 const float* __restrict__ emb,
                                                 const float* __restrict__ w_rel,
                                                 const float* __restrict__ w_root,
                                                 const int* __restrict__ src,
                                                 const int* __restrict__ dst,
                                                 const int* __restrict__ et,
                                                 unsigned* __restrict__ h,
                                                 unsigned short* __restrict__ wb,
                                                 int* __restrict__ bcur,
                                                 unsigned* __restrict__ stage) {
    __shared__ int lcnt[256];
    __shared__ int loff[256];
    __shared__ int lcur[256];
    __shared__ int sbase[256];
    __shared__ int wsum[4];
    __shared__ unsigned srt[EPB];          // 6.4 KB
    __shared__ unsigned char bkt[EPB];     // 1.6 KB

    int tid = threadIdx.x;
    if (blockIdx.x >= BIN_BLOCKS) {
        int i = (blockIdx.x - BIN_BLOCKS) * 256 + tid;
        if (i < PREP_G) {
            int n = i >> 6, dw = i & 63;
            float2 v = *(const float2*)&emb[(size_t)x[n] * ND + 2 * dw];
            h[i] = pack2(v.x, v.y);
            return;
        }
        i -= PREP_G;
        if (i < PREP_W) {
            int m = i >> 14;
            int idx = i & 16383;
            int j = idx & 7;
            int lane = (idx >> 3) & 63;
            int ft = (idx >> 9) & 7;
            int kk = idx >> 12;
            int row = kk * 32 + (lane >> 4) * 8 + j;
            int col = ft * 16 + (lane & 15);
            const float* W = (m < 24) ? (w_rel + (size_t)m * 16384)
                                      : (w_root + (size_t)(m - 24) * 16384);
            wb[i] = (unsigned short)f2bf(W[row * ND + col]);
        }
        return;
    }

    // ---- binA: LDS counting sort by coarse bucket of key = dst*8+et ----
    lcnt[tid] = 0;
    __syncthreads();

    int base4 = blockIdx.x * I4PB;
    const int4* s4p = (const int4*)src;
    const int4* d4p = (const int4*)dst;
    const int4* t4p = (const int4*)et;

    for (int i4 = tid; i4 < I4PB; i4 += 256) {
        int4 d4 = d4p[base4 + i4];
        int4 t4 = t4p[base4 + i4];
        atomicAdd(&lcnt[(d4.x * 8 + t4.x) >> BSH], 1);
        atomicAdd(&lcnt[(d4.y * 8 + t4.y) >> BSH], 1);
        atomicAdd(&lcnt[(d4.z * 8 + t4.z) >> BSH], 1);
        atomicAdd(&lcnt[(d4.w * 8 + t4.w) >> BSH], 1);
    }
    __syncthreads();
    int own = lcnt[tid];
    int excl = wave_excl_scan256(own, tid, wsum);
    loff[tid] = excl;
    lcur[tid] = excl;
    if (tid < NBKT) sbase[tid] = atomicAdd(&bcur[tid], own);
    __syncthreads();

    for (int i4 = tid; i4 < I4PB; i4 += 256) {
        int4 s4 = s4p[base4 + i4];
        int4 d4 = d4p[base4 + i4];
        int4 t4 = t4p[base4 + i4];
        int keys[4] = {d4.x * 8 + t4.x, d4.y * 8 + t4.y,
                       d4.z * 8 + t4.z, d4.w * 8 + t4.w};
        int srcs[4] = {s4.x, s4.y, s4.z, s4.w};
#pragma unroll
        for (int j = 0; j < 4; j++) {
            int key = keys[j];
            int b = key >> BSH;
            unsigned rec = ((unsigned)(key & 2047) << 16) | (unsigned)srcs[j];
            int pos = atomicAdd(&lcur[b], 1);
            srt[pos] = rec;
            bkt[pos] = (unsigned char)b;
        }
    }
    __syncthreads();
    for (int i = tid; i < EPB; i += 256) {
        int b = bkt[i];
        int idx = sbase[b] + (i - loff[b]);
        if (idx < STRIDE_PB)                     // insurance: degrade, don't fault
            stage[(size_t)b * STRIDE_PB + idx] = srt[i];
    }
}

// ---- binB: counting sort of bucket's 2048 keys; emits self-describing adj
// recs (r<<28 | deg<<16 | src) and compact nodestart[n] (key%8==0 prefixes).
// tmp[0..3] doubles as the wave-scan fixup buffer (the old 256-wide ping-pong
// scans are gone).
__device__ __forceinline__ void binB_body(const unsigned* __restrict__ stage,
                                          const int* __restrict__ bcur,
                                          int* __restrict__ nodestart,
                                          unsigned* __restrict__ adj,
                                          int b, int tid,
                                          int* tmp, int* lcnt2, int* loff2,
                                          unsigned short* srt2, int* misc) {
    int bv = (tid < NBKT) ? bcur[tid] : 0;
    int excl1 = wave_excl_scan256(bv, tid, tmp);
    if (tid == b) { misc[0] = excl1; misc[1] = bv; }
    for (int j = tid; j < 2048; j += 256) lcnt2[j] = 0;
    __syncthreads();

    int n = misc[1];
    n = n < STRIDE_PB ? n : STRIDE_PB;           // insurance
    const unsigned* sp = stage + (size_t)b * STRIDE_PB;
    for (int i = tid; i < n; i += 256)
        atomicAdd(&lcnt2[sp[i] >> 16], 1);
    __syncthreads();

    int v8[8];
    int s8 = 0;
    int base8 = tid * 8;
#pragma unroll
    for (int j = 0; j < 8; j++) { v8[j] = lcnt2[base8 + j]; s8 += v8[j]; }
    int run = wave_excl_scan256(s8, tid, tmp);
#pragma unroll
    for (int j = 0; j < 8; j++) { loff2[base8 + j] = run; run += v8[j]; }
    __syncthreads();
    for (int j = tid; j < 2048; j += 256) lcnt2[j] = loff2[j];   // cursor
    __syncthreads();

    for (int i = tid; i < n; i += 256) {
        unsigned rec = sp[i];
        int pos = atomicAdd(&lcnt2[rec >> 16], 1);
        srt2[pos] = (unsigned short)(rec & 0xFFFFu);
    }
    __syncthreads();

    int gb = misc[0];
    int segbase = b << BSH;
#pragma unroll
    for (int jj = 0; jj < 8; jj++) {
        int j = base8 + jj;
        int key = segbase + j;
        if (key >= RN) break;
        int s = loff2[j], e = lcnt2[j];
        int d = e - s; d = d > 4095 ? 4095 : d;
        unsigned tag = ((unsigned)(key & 7) << 28) | ((unsigned)d << 16);
        for (int i = s; i < e; i++) adj[gb + i] = tag | (unsigned)srt2[i];
        if ((key & 7) == 0) nodestart[key >> 3] = gb + s;
    }
    if (b == NBKT - 1 && tid == 0) nodestart[NN] = NE;
}

typedef unsigned TRarr[16][66];

// ---- mm: NG row-groups (64 rows) per block. W staged in TWO 16 KB halves
// (r13): LDS 32.5 KB => 4 blocks/CU.
template <int NG>
__device__ __forceinline__ void mm_body(const unsigned* __restrict__ h32,
                                        const unsigned short* __restrict__ wrel,
                                        const unsigned short* __restrict__ wroot,
                                        unsigned* __restrict__ hr,
                                        int mb, int tid,
                                        uint4* SB4, TRarr* TRp) {
    const unsigned short* SBs = (const unsigned short*)SB4;
    int wave = tid >> 6, lane = tid & 63;
    int quad = lane >> 4, l15 = lane & 15;
    int pr = l15 & 1;

    int rbase[NG];
    short8 af[NG][4];
#pragma unroll
    for (int g = 0; g < NG; g++) {
        rbase[g] = mb * (64 * NG) + g * 64 + wave * 16;
        int gi = rbase[g] + l15; gi = gi < NN ? gi : NN - 1;
        const unsigned* H = h32 + (size_t)gi * 64;
#pragma unroll
        for (int kk = 0; kk < 4; kk++)
            af[g][kk] = *(const short8*)&H[kk * 16 + quad * 4];
    }

    for (int m = 0; m < 9; m++) {
        const unsigned short* W = (m < 8) ? (wrel + (size_t)m * 16384) : wroot;
        const uint4* Wg = (const uint4*)W;

        float4v ac[NG][8];
#pragma unroll
        for (int g = 0; g < NG; g++)
#pragma unroll
            for (int i = 0; i < 8; i++) ac[g][i] = (float4v){0.f, 0.f, 0.f, 0.f};

#pragma unroll
        for (int half = 0; half < 2; half++) {
            __syncthreads();                         // prev stage's reads done
#pragma unroll
            for (int i = 0; i < 4; i++)
                SB4[tid + 256 * i] = Wg[half * 1024 + tid + 256 * i];
            __syncthreads();
#pragma unroll
            for (int kloc = 0; kloc < 2; kloc++) {
                int kk = half * 2 + kloc;
#pragma unroll
                for (int ft = 0; ft < 8; ft++) {
                    short8 bf = *(const short8*)&SBs[((kloc * 8 + ft) * 64 + lane) * 8];
#pragma unroll
                    for (int g = 0; g < NG; g++)
                        ac[g][ft] = __builtin_amdgcn_mfma_f32_16x16x32_bf16(af[g][kk], bf, ac[g][ft], 0, 0, 0);
                }
            }
        }

        unsigned* hrm = hr + (size_t)m * NN * 64;
#pragma unroll
        for (int g = 0; g < NG; g++) {
            // pack + wave-private transpose (no barrier: same-wave order)
#pragma unroll
            for (int ft = 0; ft < 8; ft++) {
                float4v part;
#pragma unroll
                for (int rg = 0; rg < 4; rg++) part[rg] = __shfl_xor(ac[g][ft][rg], 1, 64);
                if ((ft & 1) == pr) {
                    int a = l15 >> 1;
#pragma unroll
                    for (int rg = 0; rg < 4; rg++) {
                        float lo = pr ? part[rg] : ac[g][ft][rg];
                        float hi = pr ? ac[g][ft][rg] : part[rg];
                        TRp[wave][quad * 4 + rg][ft * 8 + a] = pack2(lo, hi);
                    }
                }
            }
#pragma unroll
            for (int ps = 0; ps < 4; ps++) {
                int ri = ps * 4 + quad;
                uint4 v = *(const uint4*)&TRp[wave][ri][l15 * 4];
                int row = rbase[g] + ri;
                if (row < NN)
                    *(uint4*)&hrm[(size_t)row * 64 + l15 * 4] = v;
            }
        }
    }
}

// ---- launch 2: binB (blocks [0,196)) || mm layer 0 (NG=1) ----
__global__ __launch_bounds__(256) void k_binB_mm(const unsigned* __restrict__ stage,
                                                 const int* __restrict__ bcur,
                                                 int* __restrict__ nodestart,
                                                 unsigned* __restrict__ adj,
                                                 const unsigned* __restrict__ h32,
                                                 const unsigned short* __restrict__ wrel,
                                                 const unsigned short* __restrict__ wroot,
                                                 unsigned* __restrict__ hr) {
    __shared__ uint4 SMEM[2369];   // 37904 B
    int tid = threadIdx.x;
    if (blockIdx.x < NBKT) {
        int* tmp = (int*)SMEM;
        int* lcnt2 = (int*)SMEM + 256;
        int* loff2 = (int*)SMEM + 2304;
        unsigned short* srt2 = (unsigned short*)((int*)SMEM + 4352);
        int* misc = (int*)SMEM + 9472;
        binB_body(stage, bcur, nodestart, adj, blockIdx.x, tid,
                  tmp, lcnt2, loff2, srt2, misc);
    } else {
        mm_body<1>(h32, wrel, wroot, hr, blockIdx.x - NBKT, tid,
                   SMEM, (TRarr*)(SMEM + 1024));
    }
}

__global__ __launch_bounds__(256) void k_mm(const unsigned* __restrict__ h32,
                                            const unsigned short* __restrict__ wrel,
                                            const unsigned short* __restrict__ wroot,
                                            unsigned* __restrict__ hr) {
    __shared__ uint4 SMEM[2080];   // 33280 B => 4 blocks/CU
    mm_body<2>(h32, wrel, wroot, hr, blockIdx.x, threadIdx.x,
               SMEM, (TRarr*)(SMEM + 1024));
}

// per-edge scaled accumulate: 8 unpack + 8 FMA, scale = 1/deg folded in
#define AGS_A(u, s)                                        \
    a0 += bflo(u.x) * s; a1 += bfhi(u.x) * s;              \
    a2 += bflo(u.y) * s; a3 += bfhi(u.y) * s;              \
    a4 += bflo(u.z) * s; a5 += bfhi(u.z) * s;              \
    a6 += bflo(u.w) * s; a7 += bfhi(u.w) * s;
#define AGS_C(u, s)                                        \
    c0 += bflo(u.x) * s; c1 += bfhi(u.x) * s;              \
    c2 += bflo(u.y) * s; c3 += bfhi(u.y) * s;              \
    c4 += bflo(u.z) * s; c5 += bfhi(u.z) * s;              \
    c6 += bflo(u.w) * s; c7 += bfhi(u.w) * s;

// aggln r14: 8-edge unroll with __launch_bounds__(256,8) pinning VGPR<=64.
// occ x MLP is the latency product: unpinned 8-wide would drift >64 VGPR and
// halve occupancy (wash); pinned, MLP doubles at constant 8 waves/SIMD.
// 16-lane quad, 16B/lane loads (r10: width dominates divergence).
__global__ __launch_bounds__(256, 8) void k_aggln(const unsigned* __restrict__ hr,
                                               unsigned* __restrict__ h32,
                                               const unsigned* __restrict__ adj,
                                               const int* __restrict__ nodestart,
                                               const float* __restrict__ bias,
                                               const float* __restrict__ gamma,
                                               const float* __restrict__ beta,
                                               float* __restrict__ out_f,
                                               int add_res, int last) {
    int n = (blockIdx.x * 256 + threadIdx.x) >> 4;   // grid exact: 3125*256/16
    int l15 = threadIdx.x & 15;

    int st = nodestart[n], en = nodestart[n + 1];
    st = st < 0 ? 0 : st;
    en = en > NE ? NE : en;

    float a0 = 0.f, a1 = 0.f, a2 = 0.f, a3 = 0.f,
          a4 = 0.f, a5 = 0.f, a6 = 0.f, a7 = 0.f;
    float c0 = 0.f, c1 = 0.f, c2 = 0.f, c3 = 0.f,
          c4 = 0.f, c5 = 0.f, c6 = 0.f, c7 = 0.f;

    int p = st;
    for (; p + 7 < en; p += 8) {
        unsigned q0 = adj[p],     q1 = adj[p + 1];
        unsigned q2 = adj[p + 2], q3 = adj[p + 3];
        unsigned q4 = adj[p + 4], q5 = adj[p + 5];
        unsigned q6 = adj[p + 6], q7 = adj[p + 7];
        unsigned i0 = (q0 & 0xFFFFu) + (q0 >> 28) * NN;
        unsigned i1 = (q1 & 0xFFFFu) + (q1 >> 28) * NN;
        unsigned i2 = (q2 & 0xFFFFu) + (q2 >> 28) * NN;
        unsigned i3 = (q3 & 0xFFFFu) + (q3 >> 28) * NN;
        unsigned i4 = (q4 & 0xFFFFu) + (q4 >> 28) * NN;
        unsigned i5 = (q5 & 0xFFFFu) + (q5 >> 28) * NN;
        unsigned i6 = (q6 & 0xFFFFu) + (q6 >> 28) * NN;
        unsigned i7 = (q7 & 0xFFFFu) + (q7 >> 28) * NN;
        uint4 u0 = *(const uint4*)&hr[(size_t)i0 * 64 + l15 * 4];
        uint4 u1 = *(const uint4*)&hr[(size_t)i1 * 64 + l15 * 4];
        uint4 u2 = *(const uint4*)&hr[(size_t)i2 * 64 + l15 * 4];
        uint4 u3 = *(const uint4*)&hr[(size_t)i3 * 64 + l15 * 4];
        uint4 u4 = *(const uint4*)&hr[(size_t)i4 * 64 + l15 * 4];
        uint4 u5 = *(const uint4*)&hr[(size_t)i5 * 64 + l15 * 4];
        uint4 u6 = *(const uint4*)&hr[(size_t)i6 * 64 + l15 * 4];
        uint4 u7 = *(const uint4*)&hr[(size_t)i7 * 64 + l15 * 4];
        float s0 = __builtin_amdgcn_rcpf((float)((q0 >> 16) & 0xFFFu));
        float s1 = __builtin_amdgcn_rcpf((float)((q1 >> 16) & 0xFFFu));
        float s2 = __builtin_amdgcn_rcpf((float)((q2 >> 16) & 0xFFFu));
        float s3 = __builtin_amdgcn_rcpf((float)((q3 >> 16) & 0xFFFu));
        float s4 = __builtin_amdgcn_rcpf((float)((q4 >> 16) & 0xFFFu));
        float s5 = __builtin_amdgcn_rcpf((float)((q5 >> 16) & 0xFFFu));
        float s6 = __builtin_amdgcn_rcpf((float)((q6 >> 16) & 0xFFFu));
        float s7 = __builtin_amdgcn_rcpf((float)((q7 >> 16) & 0xFFFu));
        AGS_A(u0, s0) AGS_C(u1, s1) AGS_A(u2, s2) AGS_C(u3, s3)
        AGS_A(u4, s4) AGS_C(u5, s5) AGS_A(u6, s6) AGS_C(u7, s7)
    }
    for (; p + 3 < en; p += 4) {
        unsigned q0 = adj[p],     q1 = adj[p + 1];
        unsigned q2 = adj[p + 2], q3 = adj[p + 3];
        unsigned i0 = (q0 & 0xFFFFu) + (q0 >> 28) * NN;
        unsigned i1 = (q1 & 0xFFFFu) + (q1 >> 28) * NN;
        unsigned i2 = (q2 & 0xFFFFu) + (q2 >> 28) * NN;
        unsigned i3 = (q3 & 0xFFFFu) + (q3 >> 28) * NN;
        uint4 u0 = *(const uint4*)&hr[(size_t)i0 * 64 + l15 * 4];
        uint4 u1 = *(const uint4*)&hr[(size_t)i1 * 64 + l15 * 4];
        uint4 u2 = *(const uint4*)&hr[(size_t)i2 * 64 + l15 * 4];
        uint4 u3 = *(const uint4*)&hr[(size_t)i3 * 64 + l15 * 4];
        float s0 = __builtin_amdgcn_rcpf((float)((q0 >> 16) & 0xFFFu));
        float s1 = __builtin_amdgcn_rcpf((float)((q1 >> 16) & 0xFFFu));
        float s2 = __builtin_amdgcn_rcpf((float)((q2 >> 16) & 0xFFFu));
        float s3 = __builtin_amdgcn_rcpf((float)((q3 >> 16) & 0xFFFu));
        AGS_A(u0, s0) AGS_C(u1, s1) AGS_A(u2, s2) AGS_C(u3, s3)
    }
    for (; p + 1 < en; p += 2) {
        unsigned q0 = adj[p], q1 = adj[p + 1];
        unsigned i0 = (q0 & 0xFFFFu) + (q0 >> 28) * NN;
        unsigned i1 = (q1 & 0xFFFFu) + (q1 >> 28) * NN;
        uint4 u0 = *(const uint4*)&hr[(size_t)i0 * 64 + l15 * 4];
        uint4 u1 = *(const uint4*)&hr[(size_t)i1 * 64 + l15 * 4];
        float s0 = __builtin_amdgcn_rcpf((float)((q0 >> 16) & 0xFFFu));
        float s1 = __builtin_amdgcn_rcpf((float)((q1 >> 16) & 0xFFFu));
        AGS_A(u0, s0) AGS_C(u1, s1)
    }
    if (p < en) {
        unsigned q0 = adj[p];
        unsigned i0 = (q0 & 0xFFFFu) + (q0 >> 28) * NN;
        uint4 u0 = *(const uint4*)&hr[(size_t)i0 * 64 + l15 * 4];
        float s0 = __builtin_amdgcn_rcpf((float)((q0 >> 16) & 0xFFFu));
        AGS_A(u0, s0)
    }

    float t0 = a0 + c0, t1 = a1 + c1, t2 = a2 + c2, t3 = a3 + c3,
          t4 = a4 + c4, t5 = a5 + c5, t6 = a6 + c6, t7 = a7 + c7;

    // root row + bias
    {
        uint4 u = *(const uint4*)&hr[((size_t)8 * NN + n) * 64 + l15 * 4];
        t0 += bflo(u.x); t1 += bfhi(u.x);
        t2 += bflo(u.y); t3 += bfhi(u.y);
        t4 += bflo(u.z); t5 += bfhi(u.z);
        t6 += bflo(u.w); t7 += bfhi(u.w);
    }
    int f0 = 8 * l15;
    {
        float4 b0 = *(const float4*)&bias[f0];
        float4 b1 = *(const float4*)&bias[f0 + 4];
        t0 += b0.x; t1 += b0.y; t2 += b0.z; t3 += b0.w;
        t4 += b1.x; t5 += b1.y; t6 += b1.z; t7 += b1.w;
    }

    float s = t0 + t1 + t2 + t3 + t4 + t5 + t6 + t7;
#pragma unroll
    for (int off = 1; off < 16; off <<= 1) s += __shfl_xor(s, off, 64);
    float mu = s * (1.0f / ND);
    float e0 = t0 - mu, e1 = t1 - mu, e2 = t2 - mu, e3 = t3 - mu,
          e4 = t4 - mu, e5 = t5 - mu, e6 = t6 - mu, e7 = t7 - mu;
    float vs = e0 * e0 + e1 * e1 + e2 * e2 + e3 * e3 +
               e4 * e4 + e5 * e5 + e6 * e6 + e7 * e7;
#pragma unroll
    for (int off = 1; off < 16; off <<= 1) vs += __shfl_xor(vs, off, 64);
    float rr = rsqrtf(vs * (1.0f / ND) + LN_EPS);

    float4 g0 = *(const float4*)&gamma[f0];
    float4 g1 = *(const float4*)&gamma[f0 + 4];
    float4 be0 = *(const float4*)&beta[f0];
    float4 be1 = *(const float4*)&beta[f0 + 4];
    float o0 = fmaxf(e0 * rr * g0.x + be0.x, 0.0f);
    float o1 = fmaxf(e1 * rr * g0.y + be0.y, 0.0f);
    float o2 = fmaxf(e2 * rr * g0.z + be0.z, 0.0f);
    float o3 = fmaxf(e3 * rr * g0.w + be0.w, 0.0f);
    float o4 = fmaxf(e4 * rr * g1.x + be1.x, 0.0f);
    float o5 = fmaxf(e5 * rr * g1.y + be1.y, 0.0f);
    float o6 = fmaxf(e6 * rr * g1.z + be1.z, 0.0f);
    float o7 = fmaxf(e7 * rr * g1.w + be1.w, 0.0f);

    if (add_res) {
        uint4 u = *(const uint4*)&h32[(size_t)n * 64 + l15 * 4];
        o0 += bflo(u.x); o1 += bfhi(u.x);
        o2 += bflo(u.y); o3 += bfhi(u.y);
        o4 += bflo(u.z); o5 += bfhi(u.z);
        o6 += bflo(u.w); o7 += bfhi(u.w);
    }
    if (last) {
        *(float4*)&out_f[(size_t)n * ND + f0] = make_float4(o0, o1, o2, o3);
        *(float4*)&out_f[(size_t)n * ND + f0 + 4] = make_float4(o4, o5, o6, o7);
    } else {
        uint4 w;
        w.x = pack2(o0, o1); w.y = pack2(o2, o3);
        w.z = pack2(o4, o5); w.w = pack2(o6, o7);
        *(uint4*)&h32[(size_t)n * 64 + l15 * 4] = w;
    }
}

extern "C" void kernel_launch(void* const* d_in, const int* in_sizes, int n_in,
                              void* d_out, int out_size, void* d_ws, size_t ws_size,
                              hipStream_t stream) {
    const int*   x      = (const int*)d_in[0];
    const int*   ei     = (const int*)d_in[1];
    const int*   et     = (const int*)d_in[2];
    const float* emb    = (const float*)d_in[3];
    const float* w_rel  = (const float*)d_in[4];
    const float* w_root = (const float*)d_in[5];
    const float* bias   = (const float*)d_in[6];
    const float* gamma  = (const float*)d_in[7];
    const float* beta   = (const float*)d_in[8];
    float* out = (float*)d_out;

    char* ws = (char*)d_ws;
    unsigned* h         = (unsigned*)(ws + WS_H);     // 12.8 MB bf16x2 rows
    int*      nodestart = (int*)     (ws + WS_NS);    // (NN+1) ints
    int*      bcur      = (int*)     (ws + WS_BCUR);  // 784 B
    unsigned* adj       = (unsigned*)(ws + WS_ADJ);   // 6.4 MB packed recs
    unsigned short* wb  = (unsigned short*)(ws + WS_WB);  // 884736 B
    unsigned* big       = (unsigned*)(ws + WS_BIG);   // hr 115.2 MB
    unsigned* stage     = (unsigned*)d_out;           // 8 MB (dead until last aggln)

    const int* src = ei;
    const int* dst = ei + NE;

    hipMemsetAsync(bcur, 0, NBKT * sizeof(int), stream);   // MUST precede binA atomics

    k_prepbin<<<BIN_BLOCKS + PREP_BLOCKS, 256, 0, stream>>>(
        x, emb, w_rel, w_root, src, dst, et, h, wb, bcur, stage);

    k_binB_mm<<<NBKT + MM_BLOCKS_FU, 256, 0, stream>>>(
        stage, bcur, nodestart, adj,
        h, wb, wb + (size_t)24 * 16384, big);
    k_aggln<<<NN * 16 / 256, 256, 0, stream>>>(
        big, h, adj, nodestart,
        bias, gamma, beta, out, 0, 0);
    for (int l = 1; l < NL; l++) {
        k_mm<<<MM_BLOCKS_SA, 256, 0, stream>>>(
            h, wb + (size_t)l * 8 * 16384, wb + (size_t)(24 + l) * 16384, big);
        k_aggln<<<NN * 16 / 256, 256, 0, stream>>>(
            big, h, adj, nodestart,
            bias + l * ND, gamma + l * ND, beta + l * ND,
            out, 1, l == NL - 1);
    }
}